// Round 1
// baseline (126.279 us; speedup 1.0000x reference)
//
#include <hip/hip_runtime.h>
#include <hip/hip_cooperative_groups.h>
#include <math.h>

namespace cg = cooperative_groups;

// (B,T,N,D) = (16,100,128,3), fp32 in, fp32 scalar out.
constexpr int B = 16, T = 100, N = 128;
constexpr float MIN_DIST  = 0.05f;
constexpr float MIN_DIST2 = MIN_DIST * MIN_DIST;

constexpr int THREADS = 256;
constexpr int G       = 800;                 // 2 pen slices/block; <=4 blocks/CU -> coop-safe

constexpr int PER_B = T * N * 3;             // 38400 floats per batch
constexpr int PER_T = N * 3;                 // 384 floats per slice

// misc decomposition (single item per thread: G*THREADS = 204800 >= MISC_TOTAL)
constexpr int WORK_V4_PER_B = (T - 1) * N * 3 / 4;    // 9504 float4 per batch
constexpr int WORK_V4 = B * WORK_V4_PER_B;            // 152064
constexpr int KE_V4_PER_SLICE = N * 3 / 4;            // 96
constexpr int KE_V4  = 2 * B * KE_V4_PER_SLICE;       // 3072
constexpr int STAB_V = B * 5 * N;                     // 10240
constexpr int MISC_TOTAL = WORK_V4 + STAB_V + KE_V4;  // 165376

constexpr int WORK_N = B * (T - 1) * N;               // 202752

__device__ __forceinline__ float wave_sum(float v) {
#pragma unroll
    for (int off = 32; off > 0; off >>= 1) v += __shfl_down(v, off, 64);
    return v;
}

template <bool COOP>
__global__ __launch_bounds__(THREADS, 4) void physics_one(
    const float* __restrict__ traj, const float* __restrict__ vel,
    const float* __restrict__ frc, float* __restrict__ ws,
    float* __restrict__ out)
{
    __shared__ float  sraw[2 * PER_T];   // both slices' raw floats, coalesced-staged
    __shared__ float4 spos[2][N];
    __shared__ float  red[5][4];

    const int tid  = threadIdx.x;
    const int bid  = blockIdx.x;
    const int lane = tid & 63;
    const int wv   = tid >> 6;

    // ---- stage BOTH pen slices (bid, bid+G): 192 coalesced float4 loads ----
    if (tid < 192) {
        const int s  = tid >= 96;
        const int r  = tid - s * 96;
        const int pb = bid + s * G;
        ((float4*)sraw)[tid] = ((const float4*)traj)[pb * (PER_T / 4) + r];
    }
    __syncthreads();
    {   // repack: one float4 per point (b128-friendly), stride-3 reads are conflict-free
        const int s = tid >> 7, p = tid & (N - 1);
        const float* rb = sraw + s * PER_T;
        spos[s][p] = make_float4(rb[p * 3], rb[p * 3 + 1], rb[p * 3 + 2], 0.f);
    }
    __syncthreads();

    // ---- issue this thread's single misc load NOW (flies under pen compute) ----
    const int v = bid * THREADS + tid;
    int cat = 3, which = 0;
    float4 mf, mt0, mt1;
    float  e0 = 0.f, e1 = 0.f, e2 = 0.f;
    {
        const float4* t4 = (const float4*)traj;
        const float4* f4 = (const float4*)frc;
        const float4* v4 = (const float4*)vel;
        if (v < WORK_V4) {
            cat = 0;
            const int b = v / WORK_V4_PER_B;
            const int r = v - b * WORK_V4_PER_B;
            const int base = b * (PER_B / 4) + r;
            mf  = f4[base];
            mt0 = t4[base];
            mt1 = t4[base + PER_T / 4];
        } else if (v < WORK_V4 + STAB_V) {
            cat = 1;
            const int s2 = v - WORK_V4;
            const int b  = s2 / 640;             // 5*N vectors per batch
            const int r  = s2 - b * 640;
            const int e  = b * PER_B + 95 * PER_T + r * 3;
            e0 = vel[e]; e1 = vel[e + 1]; e2 = vel[e + 2];
        } else if (v < MISC_TOTAL) {
            cat = 2;
            const int s2 = v - WORK_V4 - STAB_V;  // [0,3072)
            which        = s2 / 1536;             // 0 -> t=0, 1 -> t=T-1
            const int rr = s2 - which * 1536;
            const int b  = rr / KE_V4_PER_SLICE;
            const int r  = rr - b * KE_V4_PER_SLICE;
            mf = v4[b * (PER_B / 4) + which * (99 * PER_T / 4) + r];
        }
    }

    // ---- penetration: wrap partition over unordered pairs, both slices ----
    const int i    = tid & (N - 1);
    const int half = tid >> 7;
    const int k0   = 1 + half * 32;
    const int k1   = 32 + half * 31;           // half0: 1..32, half1: 33..63
    float pen = 0.f;
#pragma unroll
    for (int s = 0; s < 2; ++s) {
        const float4 pi = spos[s][i];
#pragma unroll 8
        for (int k = k0; k <= k1; ++k) {
            const int j = (i + k) & (N - 1);   // stride-1 across lanes
            const float4 pj = spos[s][j];
            const float dx = pi.x - pj.x, dy = pi.y - pj.y, dz = pi.z - pj.z;
            const float d2 = dx * dx + dy * dy + dz * dz;
            const bool h = d2 < MIN_DIST2;
            if (__builtin_expect(__any(h), 0))  // hits ~1e-5/pair
                if (h) pen += MIN_DIST - sqrtf(d2);
        }
        if (half) {                             // k = 64 diagonal, count once
            const float4 pj = spos[s][(i + 64) & (N - 1)];
            const float dx = pi.x - pj.x, dy = pi.y - pj.y, dz = pi.z - pj.z;
            const float d2 = dx * dx + dy * dy + dz * dz;
            const bool h = (d2 < MIN_DIST2) & (i < 64);
            if (__builtin_expect(__any(h), 0))
                if (h) pen += MIN_DIST - sqrtf(d2);
        }
    }

    // ---- misc compute from the held registers ----
    float sw = 0.f, ss = 0.f, ka = 0.f, kb = 0.f;
    if (cat == 0) {
        sw = mf.x * (mt1.x - mt0.x) + mf.y * (mt1.y - mt0.y)
           + mf.z * (mt1.z - mt0.z) + mf.w * (mt1.w - mt0.w);
    } else if (cat == 1) {
        ss = sqrtf(e0 * e0 + e1 * e1 + e2 * e2);
    } else if (cat == 2) {
        const float k = mf.x * mf.x + mf.y * mf.y + mf.z * mf.z + mf.w * mf.w;
        if (which) kb = k; else ka = k;
    }

    // ---- block reduction of 5 partials ----
    float vals[5] = {pen, sw, ss, ka, kb};
#pragma unroll
    for (int q = 0; q < 5; ++q) {
        const float w = wave_sum(vals[q]);
        if (lane == 0) red[q][wv] = w;
    }
    __syncthreads();
    if (tid < 5)
        ws[tid * G + bid] = red[tid][0] + red[tid][1] + red[tid][2] + red[tid][3];

    if constexpr (!COOP) return;

    cg::this_grid().sync();
    if (bid != 0) return;

    // ---- finalize in block 0 ----
    float acc[5] = {0.f, 0.f, 0.f, 0.f, 0.f};
    for (int idx = tid; idx < G; idx += THREADS) {
#pragma unroll
        for (int q = 0; q < 5; ++q) acc[q] += ws[q * G + idx];
    }
#pragma unroll
    for (int q = 0; q < 5; ++q) {
        const float w = wave_sum(acc[q]);
        if (lane == 0) red[q][wv] = w;
    }
    __syncthreads();
    if (tid == 0) {
        const float pen_t = red[0][0] + red[0][1] + red[0][2] + red[0][3];
        const float wk    = red[1][0] + red[1][1] + red[1][2] + red[1][3];
        const float st    = red[2][0] + red[2][1] + red[2][2] + red[2][3];
        const float k0s   = red[3][0] + red[3][1] + red[3][2] + red[3][3];
        const float k1s   = red[4][0] + red[4][1] + red[4][2] + red[4][3];
        const float pen_loss  = pen_t / (float)((long long)B * T * (N * (N - 1) / 2));
        const float stab_loss = st / (float)STAB_V;
        const float ke_s = 0.5f * k0s / (float)(B * N);
        const float ke_e = 0.5f * k1s / (float)(B * N);
        const float work = wk / (float)WORK_N;
        out[0] = 10.0f * pen_loss + stab_loss + 0.1f * fabsf(ke_e - ke_s - work);
    }
}

// fallback finalize (only used if cooperative enqueue is rejected)
__global__ __launch_bounds__(THREADS) void physics_fin(
    const float* __restrict__ ws, float* __restrict__ out)
{
    __shared__ float red[5][4];
    const int tid = threadIdx.x, lane = tid & 63, wv = tid >> 6;
    float acc[5] = {0.f, 0.f, 0.f, 0.f, 0.f};
    for (int idx = tid; idx < G; idx += THREADS) {
#pragma unroll
        for (int q = 0; q < 5; ++q) acc[q] += ws[q * G + idx];
    }
#pragma unroll
    for (int q = 0; q < 5; ++q) {
        const float w = wave_sum(acc[q]);
        if (lane == 0) red[q][wv] = w;
    }
    __syncthreads();
    if (tid == 0) {
        const float pen_t = red[0][0] + red[0][1] + red[0][2] + red[0][3];
        const float wk    = red[1][0] + red[1][1] + red[1][2] + red[1][3];
        const float st    = red[2][0] + red[2][1] + red[2][2] + red[2][3];
        const float k0s   = red[3][0] + red[3][1] + red[3][2] + red[3][3];
        const float k1s   = red[4][0] + red[4][1] + red[4][2] + red[4][3];
        const float pen_loss  = pen_t / (float)((long long)B * T * (N * (N - 1) / 2));
        const float stab_loss = st / (float)STAB_V;
        const float ke_s = 0.5f * k0s / (float)(B * N);
        const float ke_e = 0.5f * k1s / (float)(B * N);
        const float work = wk / (float)WORK_N;
        out[0] = 10.0f * pen_loss + stab_loss + 0.1f * fabsf(ke_e - ke_s - work);
    }
}

extern "C" void kernel_launch(void* const* d_in, const int* in_sizes, int n_in,
                              void* d_out, int out_size, void* d_ws, size_t ws_size,
                              hipStream_t stream) {
    const float* traj = (const float*)d_in[0];
    const float* vel  = (const float*)d_in[1];
    const float* frc  = (const float*)d_in[2];
    float* out = (float*)d_out;
    float* ws  = (float*)d_ws;

    void* args[] = {(void*)&traj, (void*)&vel, (void*)&frc, (void*)&ws, (void*)&out};
    const hipError_t err = hipLaunchCooperativeKernel(
        (const void*)physics_one<true>, dim3(G), dim3(THREADS), args, 0, stream);
    if (err != hipSuccess) {
        // degrade to the verified two-dispatch path
        physics_one<false><<<G, THREADS, 0, stream>>>(traj, vel, frc, ws, out);
        physics_fin<<<1, THREADS, 0, stream>>>(ws, out);
    }
}

// Round 2
// 72.090 us; speedup vs baseline: 1.7517x; 1.7517x over previous
//
#include <hip/hip_runtime.h>
#include <math.h>

// (B,T,N,D) = (16,100,128,3), fp32 in, fp32 scalar out.
constexpr int B = 16, T = 100, N = 128;
constexpr float MIN_DIST  = 0.05f;
constexpr float MIN_DIST2 = MIN_DIST * MIN_DIST;

constexpr int THREADS = 256;
constexpr int G       = 800;                 // 2 pen slices/block; 800 blocks co-resident

constexpr int PER_B = T * N * 3;             // 38400 floats per batch
constexpr int PER_T = N * 3;                 // 384 floats per slice

// misc decomposition (single item per thread: G*THREADS = 204800 >= MISC_TOTAL)
constexpr int WORK_V4_PER_B = (T - 1) * N * 3 / 4;    // 9504 float4 per batch
constexpr int WORK_V4 = B * WORK_V4_PER_B;            // 152064
constexpr int KE_V4_PER_SLICE = N * 3 / 4;            // 96
constexpr int KE_V4  = 2 * B * KE_V4_PER_SLICE;       // 3072
constexpr int STAB_V = B * 5 * N;                     // 10240
constexpr int MISC_TOTAL = WORK_V4 + STAB_V + KE_V4;  // 165376

constexpr int WORK_N = B * (T - 1) * N;               // 202752

__device__ __forceinline__ float wave_sum(float v) {
#pragma unroll
    for (int off = 32; off > 0; off >>= 1) v += __shfl_down(v, off, 64);
    return v;
}

// Main kernel: 800 blocks. Each block handles 2 penetration slices (bid, bid+G)
// plus one misc (work/stab/ke) item per thread. Misc loads are issued FIRST so
// the ~500 cy HBM latency hides under LDS staging + pen compute (T14 pattern).
// No grid.sync: measured 58.6 us with coop sync vs ~4 us of actual VALU work —
// AMD grid-sync spin across 8 XCDs cost ~50 us. Two plain dispatches instead.
__global__ __launch_bounds__(THREADS, 4) void physics_one(
    const float* __restrict__ traj, const float* __restrict__ vel,
    const float* __restrict__ frc, float* __restrict__ ws)
{
    __shared__ float  sraw[2 * PER_T];   // both slices' raw floats, coalesced-staged
    __shared__ float4 spos[2][N];
    __shared__ float  red[5][4];

    const int tid  = threadIdx.x;
    const int bid  = blockIdx.x;
    const int lane = tid & 63;
    const int wv   = tid >> 6;

    // ---- issue this thread's single misc load FIRST (flies under everything) ----
    const int v = bid * THREADS + tid;
    int cat = 3, which = 0;
    float4 mf, mt0, mt1;
    float  e0 = 0.f, e1 = 0.f, e2 = 0.f;
    {
        const float4* t4 = (const float4*)traj;
        const float4* f4 = (const float4*)frc;
        const float4* v4 = (const float4*)vel;
        if (v < WORK_V4) {
            cat = 0;
            const int b = v / WORK_V4_PER_B;
            const int r = v - b * WORK_V4_PER_B;
            const int base = b * (PER_B / 4) + r;
            mf  = f4[base];
            mt0 = t4[base];
            mt1 = t4[base + PER_T / 4];
        } else if (v < WORK_V4 + STAB_V) {
            cat = 1;
            const int s2 = v - WORK_V4;
            const int b  = s2 / 640;             // 5*N vectors per batch
            const int r  = s2 - b * 640;
            const int e  = b * PER_B + 95 * PER_T + r * 3;
            e0 = vel[e]; e1 = vel[e + 1]; e2 = vel[e + 2];
        } else if (v < MISC_TOTAL) {
            cat = 2;
            const int s2 = v - WORK_V4 - STAB_V;  // [0,3072)
            which        = s2 / 1536;             // 0 -> t=0, 1 -> t=T-1
            const int rr = s2 - which * 1536;
            const int b  = rr / KE_V4_PER_SLICE;
            const int r  = rr - b * KE_V4_PER_SLICE;
            mf = v4[b * (PER_B / 4) + which * (99 * PER_T / 4) + r];
        }
    }

    // ---- stage BOTH pen slices (bid, bid+G): 192 coalesced float4 loads ----
    if (tid < 192) {
        const int s  = tid >= 96;
        const int r  = tid - s * 96;
        const int pb = bid + s * G;
        ((float4*)sraw)[tid] = ((const float4*)traj)[pb * (PER_T / 4) + r];
    }
    __syncthreads();
    {   // repack: one float4 per point (b128-friendly), stride-3 reads are conflict-free
        const int s = tid >> 7, p = tid & (N - 1);
        const float* rb = sraw + s * PER_T;
        spos[s][p] = make_float4(rb[p * 3], rb[p * 3 + 1], rb[p * 3 + 2], 0.f);
    }
    __syncthreads();

    // ---- penetration: wrap partition over unordered pairs, both slices ----
    const int i    = tid & (N - 1);
    const int half = tid >> 7;
    const int k0   = 1 + half * 32;
    const int k1   = 32 + half * 31;           // half0: 1..32, half1: 33..63
    float pen = 0.f;
#pragma unroll
    for (int s = 0; s < 2; ++s) {
        const float4 pi = spos[s][i];
#pragma unroll 8
        for (int k = k0; k <= k1; ++k) {
            const int j = (i + k) & (N - 1);   // stride-1 across lanes
            const float4 pj = spos[s][j];
            const float dx = pi.x - pj.x, dy = pi.y - pj.y, dz = pi.z - pj.z;
            const float d2 = dx * dx + dy * dy + dz * dz;
            const bool h = d2 < MIN_DIST2;
            if (__builtin_expect(__any(h), 0))  // hits ~1e-5/pair
                if (h) pen += MIN_DIST - sqrtf(d2);
        }
        if (half) {                             // k = 64 diagonal, count once
            const float4 pj = spos[s][(i + 64) & (N - 1)];
            const float dx = pi.x - pj.x, dy = pi.y - pj.y, dz = pi.z - pj.z;
            const float d2 = dx * dx + dy * dy + dz * dz;
            const bool h = (d2 < MIN_DIST2) & (i < 64);
            if (__builtin_expect(__any(h), 0))
                if (h) pen += MIN_DIST - sqrtf(d2);
        }
    }

    // ---- misc compute from the held registers ----
    float sw = 0.f, ss = 0.f, ka = 0.f, kb = 0.f;
    if (cat == 0) {
        sw = mf.x * (mt1.x - mt0.x) + mf.y * (mt1.y - mt0.y)
           + mf.z * (mt1.z - mt0.z) + mf.w * (mt1.w - mt0.w);
    } else if (cat == 1) {
        ss = sqrtf(e0 * e0 + e1 * e1 + e2 * e2);
    } else if (cat == 2) {
        const float k = mf.x * mf.x + mf.y * mf.y + mf.z * mf.z + mf.w * mf.w;
        if (which) kb = k; else ka = k;
    }

    // ---- block reduction of 5 partials ----
    float vals[5] = {pen, sw, ss, ka, kb};
#pragma unroll
    for (int q = 0; q < 5; ++q) {
        const float w = wave_sum(vals[q]);
        if (lane == 0) red[q][wv] = w;
    }
    __syncthreads();
    if (tid < 5)
        ws[tid * G + bid] = red[tid][0] + red[tid][1] + red[tid][2] + red[tid][3];
}

__global__ __launch_bounds__(THREADS) void physics_fin(
    const float* __restrict__ ws, float* __restrict__ out)
{
    __shared__ float red[5][4];
    const int tid = threadIdx.x, lane = tid & 63, wv = tid >> 6;
    float acc[5] = {0.f, 0.f, 0.f, 0.f, 0.f};
    for (int idx = tid; idx < G; idx += THREADS) {
#pragma unroll
        for (int q = 0; q < 5; ++q) acc[q] += ws[q * G + idx];
    }
#pragma unroll
    for (int q = 0; q < 5; ++q) {
        const float w = wave_sum(acc[q]);
        if (lane == 0) red[q][wv] = w;
    }
    __syncthreads();
    if (tid == 0) {
        const float pen_t = red[0][0] + red[0][1] + red[0][2] + red[0][3];
        const float wk    = red[1][0] + red[1][1] + red[1][2] + red[1][3];
        const float st    = red[2][0] + red[2][1] + red[2][2] + red[2][3];
        const float k0s   = red[3][0] + red[3][1] + red[3][2] + red[3][3];
        const float k1s   = red[4][0] + red[4][1] + red[4][2] + red[4][3];
        const float pen_loss  = pen_t / (float)((long long)B * T * (N * (N - 1) / 2));
        const float stab_loss = st / (float)STAB_V;
        const float ke_s = 0.5f * k0s / (float)(B * N);
        const float ke_e = 0.5f * k1s / (float)(B * N);
        const float work = wk / (float)WORK_N;
        out[0] = 10.0f * pen_loss + stab_loss + 0.1f * fabsf(ke_e - ke_s - work);
    }
}

extern "C" void kernel_launch(void* const* d_in, const int* in_sizes, int n_in,
                              void* d_out, int out_size, void* d_ws, size_t ws_size,
                              hipStream_t stream) {
    const float* traj = (const float*)d_in[0];
    const float* vel  = (const float*)d_in[1];
    const float* frc  = (const float*)d_in[2];
    float* out = (float*)d_out;
    float* ws  = (float*)d_ws;

    physics_one<<<G, THREADS, 0, stream>>>(traj, vel, frc, ws);
    physics_fin<<<1, THREADS, 0, stream>>>(ws, out);
}

// Round 3
// 69.829 us; speedup vs baseline: 1.8084x; 1.0324x over previous
//
#include <hip/hip_runtime.h>
#include <math.h>

// (B,T,N,D) = (16,100,128,3), fp32 in, fp32 scalar out.
constexpr int B = 16, T = 100, N = 128;
constexpr float MIN_DIST  = 0.05f;
constexpr float MIN_DIST2 = MIN_DIST * MIN_DIST;

constexpr int THREADS    = 256;
constexpr int PEN_BLOCKS = B * T;            // 1600 — one (b,t) slice per block (max TLP:
                                             // pen loop is latency-bound, 33 iters/thread)
constexpr int PER_B = T * N * 3;             // 38400 floats per batch
constexpr int PER_T = N * 3;                 // 384 floats per slice

// misc decomposition: exactly one item per thread in the first 646 blocks.
constexpr int WORK_V4_PER_B = (T - 1) * N * 3 / 4;    // 9504 float4 per batch
constexpr int WORK_V4 = B * WORK_V4_PER_B;            // 152064
constexpr int KE_V4_PER_SLICE = N * 3 / 4;            // 96
constexpr int KE_V4  = 2 * B * KE_V4_PER_SLICE;       // 3072
constexpr int STAB_V = B * 5 * N;                     // 10240
constexpr int MISC_TOTAL  = WORK_V4 + STAB_V + KE_V4; // 165376 = 646*256 exactly
constexpr int MISC_BLOCKS = MISC_TOTAL / THREADS;     // 646
static_assert(MISC_BLOCKS * THREADS == MISC_TOTAL, "misc must tile exactly");

constexpr int WORK_N = B * (T - 1) * N;               // 202752

// ws layout (every slot written every call -> re-poison safe):
constexpr int MISC_OFF = PEN_BLOCKS;                  // 1600 + 4*646 = 4184 floats used

__device__ __forceinline__ float wave_sum(float v) {
#pragma unroll
    for (int off = 32; off > 0; off >>= 1) v += __shfl_down(v, off, 64);
    return v;
}

// 1600 blocks; block bid owns pen slice bid. Blocks 0..645 additionally own 256
// misc items (1 per thread), whose loads are issued FIRST so HBM latency hides
// under LDS staging + pen compute. 3 barriers/block. No grid.sync (R1: the coop
// spin across 8 XCDs cost ~50 us vs ~4 us of actual work).
__global__ __launch_bounds__(THREADS) void physics_one(
    const float* __restrict__ traj, const float* __restrict__ vel,
    const float* __restrict__ frc, float* __restrict__ ws)
{
    __shared__ float  sraw[PER_T];       // raw slice floats, coalesced-staged
    __shared__ float4 spos[N];
    __shared__ float  red[5][4];

    const int tid  = threadIdx.x;
    const int bid  = blockIdx.x;
    const int lane = tid & 63;
    const int wv   = tid >> 6;
    const bool has_misc = (bid < MISC_BLOCKS);   // wave-uniform

    // ---- issue this thread's single misc load FIRST ----
    int cat = 3, which = 0;
    float4 mf, mt0, mt1;
    float  e0 = 0.f, e1 = 0.f, e2 = 0.f;
    if (has_misc) {
        const int v = bid * THREADS + tid;       // < MISC_TOTAL by construction
        const float4* t4 = (const float4*)traj;
        const float4* f4 = (const float4*)frc;
        const float4* v4 = (const float4*)vel;
        if (v < WORK_V4) {
            cat = 0;
            const int b = v / WORK_V4_PER_B;
            const int r = v - b * WORK_V4_PER_B;
            const int base = b * (PER_B / 4) + r;
            mf  = f4[base];
            mt0 = t4[base];
            mt1 = t4[base + PER_T / 4];
        } else if (v < WORK_V4 + STAB_V) {
            cat = 1;
            const int s2 = v - WORK_V4;
            const int b  = s2 / 640;             // 5*N vectors per batch
            const int r  = s2 - b * 640;
            const int e  = b * PER_B + 95 * PER_T + r * 3;
            e0 = vel[e]; e1 = vel[e + 1]; e2 = vel[e + 2];
        } else {
            cat = 2;
            const int s2 = v - WORK_V4 - STAB_V;  // [0,3072)
            which        = s2 / 1536;             // 0 -> t=0, 1 -> t=T-1
            const int rr = s2 - which * 1536;
            const int b  = rr / KE_V4_PER_SLICE;
            const int r  = rr - b * KE_V4_PER_SLICE;
            mf = v4[b * (PER_B / 4) + which * (99 * PER_T / 4) + r];
        }
    }

    // ---- stage pen slice: 96 coalesced float4 loads ----
    if (tid < PER_T / 4)
        ((float4*)sraw)[tid] = ((const float4*)traj)[bid * (PER_T / 4) + tid];
    __syncthreads();
    if (tid < N)   // repack: one float4 per point (b128-friendly compute reads)
        spos[tid] = make_float4(sraw[tid * 3], sraw[tid * 3 + 1], sraw[tid * 3 + 2], 0.f);
    __syncthreads();

    // ---- penetration: wrap partition over unordered pairs ----
    // pair {a,b}, gap d=(b-a)&127: d<=63 counted at k=d; d>=65 at k=128-d; d=64
    // at k=64 from both ends -> mask i<64. Total 63*128+64 = 8128 pairs.
    const int i    = tid & (N - 1);
    const int half = tid >> 7;
    const int k0   = 1 + half * 32;
    const int k1   = 32 + half * 31;           // half0: 1..32, half1: 33..63
    const float4 pi = spos[i];
    float pen = 0.f;
#pragma unroll 8
    for (int k = k0; k <= k1; ++k) {
        const int j = (i + k) & (N - 1);       // stride-1 across lanes
        const float4 pj = spos[j];
        const float dx = pi.x - pj.x, dy = pi.y - pj.y, dz = pi.z - pj.z;
        const float d2 = dx * dx + dy * dy + dz * dz;
        const bool h = d2 < MIN_DIST2;
        if (__builtin_expect(__any(h), 0))      // hits ~1e-5/pair
            if (h) pen += MIN_DIST - sqrtf(d2);
    }
    if (half) {                                 // k = 64 diagonal, count once
        const float4 pj = spos[(i + 64) & (N - 1)];
        const float dx = pi.x - pj.x, dy = pi.y - pj.y, dz = pi.z - pj.z;
        const float d2 = dx * dx + dy * dy + dz * dz;
        const bool h = (d2 < MIN_DIST2) & (i < 64);
        if (__builtin_expect(__any(h), 0))
            if (h) pen += MIN_DIST - sqrtf(d2);
    }

    // ---- misc compute from the held registers ----
    float sw = 0.f, ss = 0.f, ka = 0.f, kb = 0.f;
    if (cat == 0) {
        sw = mf.x * (mt1.x - mt0.x) + mf.y * (mt1.y - mt0.y)
           + mf.z * (mt1.z - mt0.z) + mf.w * (mt1.w - mt0.w);
    } else if (cat == 1) {
        ss = sqrtf(e0 * e0 + e1 * e1 + e2 * e2);
    } else if (cat == 2) {
        const float k = mf.x * mf.x + mf.y * mf.y + mf.z * mf.z + mf.w * mf.w;
        if (which) kb = k; else ka = k;
    }

    // ---- block reduction: pen always; 4 misc partials only in misc blocks ----
    {
        const float w = wave_sum(pen);
        if (lane == 0) red[0][wv] = w;
    }
    if (has_misc) {
        float vals[4] = {sw, ss, ka, kb};
#pragma unroll
        for (int q = 0; q < 4; ++q) {
            const float w = wave_sum(vals[q]);
            if (lane == 0) red[q + 1][wv] = w;
        }
    }
    __syncthreads();
    if (tid == 0)
        ws[bid] = red[0][0] + red[0][1] + red[0][2] + red[0][3];
    if (has_misc && tid < 4)
        ws[MISC_OFF + tid * MISC_BLOCKS + bid] =
            red[tid + 1][0] + red[tid + 1][1] + red[tid + 1][2] + red[tid + 1][3];
}

__global__ __launch_bounds__(THREADS) void physics_fin(
    const float* __restrict__ ws, float* __restrict__ out)
{
    __shared__ float red[5][4];
    const int tid = threadIdx.x, lane = tid & 63, wv = tid >> 6;

    float p = 0.f;
    for (int idx = tid; idx < PEN_BLOCKS; idx += THREADS) p += ws[idx];
    float m[4] = {0.f, 0.f, 0.f, 0.f};
    for (int idx = tid; idx < MISC_BLOCKS; idx += THREADS) {
#pragma unroll
        for (int q = 0; q < 4; ++q) m[q] += ws[MISC_OFF + q * MISC_BLOCKS + idx];
    }

    {
        const float w = wave_sum(p);
        if (lane == 0) red[0][wv] = w;
    }
#pragma unroll
    for (int q = 0; q < 4; ++q) {
        const float w = wave_sum(m[q]);
        if (lane == 0) red[q + 1][wv] = w;
    }
    __syncthreads();
    if (tid == 0) {
        const float pen_t = red[0][0] + red[0][1] + red[0][2] + red[0][3];
        const float wk    = red[1][0] + red[1][1] + red[1][2] + red[1][3];
        const float st    = red[2][0] + red[2][1] + red[2][2] + red[2][3];
        const float k0s   = red[3][0] + red[3][1] + red[3][2] + red[3][3];
        const float k1s   = red[4][0] + red[4][1] + red[4][2] + red[4][3];
        const float pen_loss  = pen_t / (float)((long long)B * T * (N * (N - 1) / 2));
        const float stab_loss = st / (float)STAB_V;
        const float ke_s = 0.5f * k0s / (float)(B * N);
        const float ke_e = 0.5f * k1s / (float)(B * N);
        const float work = wk / (float)WORK_N;
        out[0] = 10.0f * pen_loss + stab_loss + 0.1f * fabsf(ke_e - ke_s - work);
    }
}

extern "C" void kernel_launch(void* const* d_in, const int* in_sizes, int n_in,
                              void* d_out, int out_size, void* d_ws, size_t ws_size,
                              hipStream_t stream) {
    const float* traj = (const float*)d_in[0];
    const float* vel  = (const float*)d_in[1];
    const float* frc  = (const float*)d_in[2];
    float* out = (float*)d_out;
    float* ws  = (float*)d_ws;

    physics_one<<<PEN_BLOCKS, THREADS, 0, stream>>>(traj, vel, frc, ws);
    physics_fin<<<1, THREADS, 0, stream>>>(ws, out);
}